// Round 10
// baseline (299.778 us; speedup 1.0000x reference)
//
#include <hip/hip_runtime.h>
#include <math.h>

#define LL 2048
#define CC 128
#define BB 16
#define UU 40
#define NT 256
#define NW 4
#define EPSF 1e-5f

// ---------------- reduction helpers ----------------
__device__ __forceinline__ float waveSum(float v) {
#pragma unroll
    for (int off = 1; off < 64; off <<= 1) v += __shfl_xor(v, off, 64);
    return v;
}
__device__ __forceinline__ float waveMax(float v) {
#pragma unroll
    for (int off = 1; off < 64; off <<= 1) v = fmaxf(v, __shfl_xor(v, off, 64));
    return v;
}
__device__ __forceinline__ float waveMin(float v) {
#pragma unroll
    for (int off = 1; off < 64; off <<= 1) v = fminf(v, __shfl_xor(v, off, 64));
    return v;
}
__device__ __forceinline__ float blockSum(float v, volatile float* scr) {
    v = waveSum(v);
    const int lane = threadIdx.x & 63, wid = threadIdx.x >> 6;
    __syncthreads();
    if (lane == 0) scr[wid] = v;
    __syncthreads();
    return scr[0] + scr[1] + scr[2] + scr[3];
}
__device__ __forceinline__ float blockMax(float v, volatile float* scr) {
    v = waveMax(v);
    const int lane = threadIdx.x & 63, wid = threadIdx.x >> 6;
    __syncthreads();
    if (lane == 0) scr[wid] = v;
    __syncthreads();
    return fmaxf(fmaxf(scr[0], scr[1]), fmaxf(scr[2], scr[3]));
}
__device__ __forceinline__ float blockMin(float v, volatile float* scr) {
    v = waveMin(v);
    const int lane = threadIdx.x & 63, wid = threadIdx.x >> 6;
    __syncthreads();
    if (lane == 0) scr[wid] = v;
    __syncthreads();
    return fminf(fminf(scr[0], scr[1]), fminf(scr[2], scr[3]));
}

// ---------------- transpose kernels ----------------
// dual: z<16 -> x[B,L,C]->xT[B,C,L] ; z>=16 -> M[B,L,C]->MT[B,C,L]
__global__ __launch_bounds__(256) void transpose_dual(
    const float* __restrict__ x,  float* __restrict__ xT,
    const float* __restrict__ M,  float* __restrict__ MT) {
    __shared__ float t[32][33];
    const int z  = blockIdx.z;
    const int b  = (z < BB) ? z : (z - BB);
    const float* in  = (z < BB) ? x  : M;
    float* outp      = (z < BB) ? xT : MT;
    const int c0 = blockIdx.x * 32, l0 = blockIdx.y * 32;
    const int lx = threadIdx.x, ly = threadIdx.y;
    const float* base = in + ((size_t)b * LL + l0) * CC + c0;
#pragma unroll
    for (int i = 0; i < 4; ++i) t[ly + i * 8][lx] = base[(size_t)(ly + i * 8) * CC + lx];
    __syncthreads();
    float* obase = outp + ((size_t)b * CC + c0) * LL + l0;
#pragma unroll
    for (int i = 0; i < 4; ++i) obase[(size_t)(ly + i * 8) * LL + lx] = t[lx][ly + i * 8];
}
__global__ __launch_bounds__(256) void transpose_out(const float* __restrict__ in,
                                                     float* __restrict__ outp) {
    __shared__ float t[32][33];
    const int b  = blockIdx.z;
    const int l0 = blockIdx.x * 32, c0 = blockIdx.y * 32;
    const int lx = threadIdx.x, ly = threadIdx.y;
    const float* base = in + ((size_t)b * CC + c0) * LL + l0;
#pragma unroll
    for (int i = 0; i < 4; ++i) t[ly + i * 8][lx] = base[(size_t)(ly + i * 8) * LL + lx];
    __syncthreads();
    float* obase = outp + ((size_t)b * LL + l0) * CC + c0;
#pragma unroll
    for (int i = 0; i < 4; ++i) obase[(size_t)(ly + i * 8) * CC + lx] = t[lx][ly + i * 8];
}

// ---------------- M aggregate kernel (R5-proven, XCD-swizzled) ----------------
__global__ __launch_bounds__(256) void agg_kernel(
    const float* __restrict__ x, const int* __restrict__ idx,
    const float* __restrict__ gWq, const float* __restrict__ gbq,
    const float* __restrict__ gWk, const float* __restrict__ gbk,
    float* __restrict__ M)
{
    __shared__ int s_idx[8 * UU];
    const int tid = threadIdx.x;
    const int g   = blockIdx.x;
    const int b   = ((g & 7) << 1) | ((g >> 3) & 1);
    const int l0  = (g >> 4) * 8;
    if (tid < 256)          s_idx[tid]       = idx[l0 * UU + tid];
    if (tid < 8 * UU - 256) s_idx[256 + tid] = idx[l0 * UU + 256 + tid];
    __syncthreads();

    const int s = tid & 31;       // c-quad: c = 4s..4s+3
    const int r = tid >> 5;       // row slot
    const int l = l0 + r;
    const float Wq = *gWq, bq = *gbq, Wk = *gWk, bk = *gbk;

    const float4* xb = (const float4*)(x + (size_t)b * LL * CC);
    float4 xo4 = xb[(size_t)l * 32 + s];
    float xo[4] = {xo4.x, xo4.y, xo4.z, xo4.w};

    float  mx[4] = {-3.4e38f, -3.4e38f, -3.4e38f, -3.4e38f};
    float  mn[4] = { 3.4e38f,  3.4e38f,  3.4e38f,  3.4e38f};
    double sm[4] = {0.0, 0.0, 0.0, 0.0};
    const int* rowp = &s_idx[r * UU];
#pragma unroll 8
    for (int u = 0; u < UU; ++u) {
        const int i = rowp[u];
        float4 xv = xb[(size_t)i * 32 + s];
        float xa[4] = {xv.x, xv.y, xv.z, xv.w};
#pragma unroll
        for (int t = 0; t < 4; ++t) {
            mx[t] = fmaxf(mx[t], xa[t]);
            mn[t] = fminf(mn[t], xa[t]);
            sm[t] += (double)xa[t];
        }
    }
    float mo[4];
#pragma unroll
    for (int t = 0; t < 4; ++t) {
        const float xH = (Wk >= 0.f) ? mx[t] : mn[t];
        const float xL = (Wk >= 0.f) ? mn[t] : mx[t];
        const float kH = __fadd_rn(__fmul_rn(xH, Wk), bk);   // = max_u k, bit-exact
        const float kL = __fadd_rn(__fmul_rn(xL, Wk), bk);   // = min_u k, bit-exact
        const float q  = __fadd_rn(__fmul_rn(xo[t], Wq), bq);
        const float t1 = __fmul_rn(q, (q >= 0.f) ? kH : kL); // = max_u f32(q*k_u)
        const double ks = (double)Wk * sm[t] + 40.0 * (double)bk;
        const float t2 = (float)(((double)q * ks) * (1.0 / 2048.0));
        mo[t] = __fsub_rn(t1, t2);
    }
    float4 Mo = make_float4(mo[0], mo[1], mo[2], mo[3]);
    ((float4*)(M + ((size_t)b * LL + l) * CC))[s] = Mo;
}

// ---------------- rowBC: ONE BLOCK (4 waves) PER ROW, u-split softmax ----------------
// MoT [B,C,L]: holds MT on entry; block overwrites its own row with the output.
// Each wave redundantly computes top-40 (identical results, no sync), then owns
// 10 softmax u's. ctx/epilogue split across waves (2 barriers + blockSums).
__global__ __launch_bounds__(NT) void rowBC(
    const float* __restrict__ xT,    // [B,C,L]
    float* MoT,                      // [B,C,L] in: M, out: result (row-exclusive)
    const float* __restrict__ gWq, const float* __restrict__ gbq,
    const float* __restrict__ gWk, const float* __restrict__ gbk,
    const float* __restrict__ gWv, const float* __restrict__ gbv,
    const float* __restrict__ gWo, const float* __restrict__ gbo,
    const float* __restrict__ gw1, const float* __restrict__ gb1,
    const float* __restrict__ gw2, const float* __restrict__ gb2,
    const float* __restrict__ gg1, const float* __restrict__ gbe1,
    const float* __restrict__ gg2, const float* __restrict__ gbe2)
{
    const int tid = threadIdx.x;
    const int ln  = tid & 63;
    const int wid = tid >> 6;
    const int r   = blockIdx.x;      // row = b*CC + c

    __shared__ __align__(16) float s_ctx[LL];
    __shared__ int   s_top[UU];
    __shared__ float s_red[NW];

    const float Wq = *gWq, bq = *gbq, Wk = *gWk, bk = *gbk;
    const float Wv = *gWv, bv = *gbv, Wo = *gWo, bo = *gbo;
    const float w1 = *gw1, b1 = *gb1, w2 = *gw2, b2 = *gb2;
    const float g1 = *gg1, be1 = *gbe1, g2 = *gg2, be2 = *gbe2;
    const float LOG2E = 1.4426950408889634f;

    const float*  xrow  = xT + (size_t)r * LL;
    const float4* xrow4 = (const float4*)xrow;
    float* Mrow = MoT + (size_t)r * LL;
    const float4* mrow4 = (const float4*)Mrow;
    float4* orow4 = (float4*)Mrow;
    float4* ctx4  = (float4*)s_ctx;

    // ---- 1: load M row into registers (element l = 4*(ln+64m)+q) — per wave
    float4 mv[8];
#pragma unroll
    for (int m = 0; m < 8; ++m) mv[m] = mrow4[ln + m * 64];

    // ---- 2: in-wave top-40 (redundant per wave; deterministic identical result)
    float bvv = -3.4e38f; int bii = LL + 1;
#pragma unroll
    for (int m = 0; m < 8; ++m) {
        const int l0 = 4 * (ln + 64 * m);
        if (mv[m].x > bvv) { bvv = mv[m].x; bii = l0; }
        if (mv[m].y > bvv) { bvv = mv[m].y; bii = l0 + 1; }
        if (mv[m].z > bvv) { bvv = mv[m].z; bii = l0 + 2; }
        if (mv[m].w > bvv) { bvv = mv[m].w; bii = l0 + 3; }
    }
    for (int t = 0; t < UU; ++t) {
        float rv = bvv; int ri = bii;
#pragma unroll
        for (int off = 1; off < 64; off <<= 1) {
            float ov = __shfl_xor(rv, off, 64);
            int   oi = __shfl_xor(ri, off, 64);
            if (ov > rv || (ov == rv && oi < ri)) { rv = ov; ri = oi; }
        }
        if (ln == 0) s_top[t] = ri;   // all 4 waves write identical values
        if (bii == ri) {              // owner lane: invalidate + rescan
#pragma unroll
            for (int m = 0; m < 8; ++m) {
                const int l0 = 4 * (ln + 64 * m);
                if (l0     == ri) mv[m].x = -3.4e38f;
                if (l0 + 1 == ri) mv[m].y = -3.4e38f;
                if (l0 + 2 == ri) mv[m].z = -3.4e38f;
                if (l0 + 3 == ri) mv[m].w = -3.4e38f;
            }
            bvv = -3.4e38f; bii = LL + 1;
#pragma unroll
            for (int m = 0; m < 8; ++m) {
                const int l0 = 4 * (ln + 64 * m);
                if (mv[m].x > bvv) { bvv = mv[m].x; bii = l0; }
                if (mv[m].y > bvv) { bvv = mv[m].y; bii = l0 + 1; }
                if (mv[m].z > bvv) { bvv = mv[m].z; bii = l0 + 2; }
                if (mv[m].w > bvv) { bvv = mv[m].w; bii = l0 + 3; }
            }
        }
    }

    // ---- 3: load x row (full, per wave); stats via monotone affine of x
    float4 xc[8];
    float vsum = 0.f, xmx = -3.4e38f, xmn = 3.4e38f;
#pragma unroll
    for (int m = 0; m < 8; ++m) {
        float4 xv = xrow4[ln + m * 64];
        xc[m] = xv;
        vsum += __fadd_rn(__fmul_rn(xv.x, Wv), bv) + __fadd_rn(__fmul_rn(xv.y, Wv), bv)
              + __fadd_rn(__fmul_rn(xv.z, Wv), bv) + __fadd_rn(__fmul_rn(xv.w, Wv), bv);
        xmx = fmaxf(xmx, fmaxf(fmaxf(xv.x, xv.y), fmaxf(xv.z, xv.w)));
        xmn = fminf(xmn, fminf(fminf(xv.x, xv.y), fminf(xv.z, xv.w)));
    }
    vsum = waveSum(vsum);
    xmx  = waveMax(xmx);
    xmn  = waveMin(xmn);
    const float vmean = vsum * (1.f / (float)LL);
    const float kmx = __fadd_rn(__fmul_rn((Wk >= 0.f) ? xmx : xmn, Wk), bk);
    const float kmn = __fadd_rn(__fmul_rn((Wk >= 0.f) ? xmn : xmx, Wk), bk);

    // ---- 4: init ctx (each wave its quarter: float4 idx [128w, 128w+128))
    const float4 vm4 = make_float4(vmean, vmean, vmean, vmean);
    ctx4[128 * wid + ln]      = vm4;
    ctx4[128 * wid + 64 + ln] = vm4;
    __syncthreads();

    // ---- 5: softmax, wave owns u = 10*wid .. 10*wid+9, two groups of 5.
    // e = exp2(A*x + B), A = qp*Wk*log2e, B = (qp*bk - smax)*log2e
#pragma unroll
    for (int g = 0; g < 2; ++g) {
        int p[5]; float A[5], Bc[5];
#pragma unroll
        for (int q = 0; q < 5; ++q) {
            p[q] = s_top[wid * 10 + g * 5 + q];
            const float xq = xrow[p[q]];
            const float qp = __fadd_rn(__fmul_rn(xq, Wq), bq);
            const float sm = (qp >= 0.f) ? __fmul_rn(qp, kmx) : __fmul_rn(qp, kmn);
            A[q]  = qp * Wk * LOG2E;
            Bc[q] = (qp * bk - sm) * LOG2E;
        }
        float se[5] = {0.f, 0.f, 0.f, 0.f, 0.f};
        float sx[5] = {0.f, 0.f, 0.f, 0.f, 0.f};
#pragma unroll
        for (int m = 0; m < 8; ++m) {
            float4 x4 = xc[m];
#pragma unroll
            for (int q = 0; q < 5; ++q) {
                float e;
                e = exp2f(fmaf(A[q], x4.x, Bc[q])); se[q] += e; sx[q] = fmaf(e, x4.x, sx[q]);
                e = exp2f(fmaf(A[q], x4.y, Bc[q])); se[q] += e; sx[q] = fmaf(e, x4.y, sx[q]);
                e = exp2f(fmaf(A[q], x4.z, Bc[q])); se[q] += e; sx[q] = fmaf(e, x4.z, sx[q]);
                e = exp2f(fmaf(A[q], x4.w, Bc[q])); se[q] += e; sx[q] = fmaf(e, x4.w, sx[q]);
            }
        }
#pragma unroll
        for (int q = 0; q < 5; ++q) {
            const float seA = waveSum(se[q]);
            const float sxA = waveSum(sx[q]);
            const float upd = (Wv * sxA + bv * seA) / seA;   // Σe·v = Wv·Σe·x + bv·Σe
            if (ln == 0) s_ctx[p[q]] = upd;
        }
    }
    __syncthreads();

    // ---- 6: epilogue, each wave its quarter (re-read x: static indices, no
    // runtime-indexed register arrays)
    const int f0 = 128 * wid + ln, f1 = f0 + 64;
    float4 xa = xrow4[f0], xb = xrow4[f1];
    float4 ca = ctx4[f0],  cb = ctx4[f1];
    float4 ta, tb;
    ta.x = xa.x + __fadd_rn(__fmul_rn(ca.x, Wo), bo);
    ta.y = xa.y + __fadd_rn(__fmul_rn(ca.y, Wo), bo);
    ta.z = xa.z + __fadd_rn(__fmul_rn(ca.z, Wo), bo);
    ta.w = xa.w + __fadd_rn(__fmul_rn(ca.w, Wo), bo);
    tb.x = xb.x + __fadd_rn(__fmul_rn(cb.x, Wo), bo);
    tb.y = xb.y + __fadd_rn(__fmul_rn(cb.y, Wo), bo);
    tb.z = xb.z + __fadd_rn(__fmul_rn(cb.z, Wo), bo);
    tb.w = xb.w + __fadd_rn(__fmul_rn(cb.w, Wo), bo);
    float lsum = ta.x + ta.y + ta.z + ta.w + tb.x + tb.y + tb.z + tb.w;
    const float mean1 = blockSum(lsum, s_red) * (1.f / (float)LL);
    float lss = 0.f;
    {
        float d0 = ta.x - mean1, d1 = ta.y - mean1, d2 = ta.z - mean1, d3 = ta.w - mean1;
        float d4 = tb.x - mean1, d5 = tb.y - mean1, d6 = tb.z - mean1, d7 = tb.w - mean1;
        lss = d0*d0 + d1*d1 + d2*d2 + d3*d3 + d4*d4 + d5*d5 + d6*d6 + d7*d7;
    }
    const float var1 = blockSum(lss, s_red) * (1.f / (float)LL);
    const float rs1 = rsqrtf(var1 + EPSF);

    float za[4], zb[4];
    {
        const float tin[8] = {ta.x, ta.y, ta.z, ta.w, tb.x, tb.y, tb.z, tb.w};
        float zo[8];
#pragma unroll
        for (int e = 0; e < 8; ++e) {
            float x1 = (tin[e] - mean1) * rs1 * g1 + be1;
            float a  = x1 * w1 + b1;
            float y  = 0.5f * a * (1.f + erff(a * 0.70710678118654752f));
            zo[e] = x1 + (y * w2 + b2);
        }
        za[0] = zo[0]; za[1] = zo[1]; za[2] = zo[2]; za[3] = zo[3];
        zb[0] = zo[4]; zb[1] = zo[5]; zb[2] = zo[6]; zb[3] = zo[7];
    }
    float lsum2 = za[0] + za[1] + za[2] + za[3] + zb[0] + zb[1] + zb[2] + zb[3];
    const float mean2 = blockSum(lsum2, s_red) * (1.f / (float)LL);
    float lss2 = 0.f;
#pragma unroll
    for (int e = 0; e < 4; ++e) {
        float d0 = za[e] - mean2, d1 = zb[e] - mean2;
        lss2 += d0 * d0 + d1 * d1;
    }
    const float var2 = blockSum(lss2, s_red) * (1.f / (float)LL);
    const float rs2 = rsqrtf(var2 + EPSF);

    float4 oa, ob;
    oa.x = (za[0] - mean2) * rs2 * g2 + be2;
    oa.y = (za[1] - mean2) * rs2 * g2 + be2;
    oa.z = (za[2] - mean2) * rs2 * g2 + be2;
    oa.w = (za[3] - mean2) * rs2 * g2 + be2;
    ob.x = (zb[0] - mean2) * rs2 * g2 + be2;
    ob.y = (zb[1] - mean2) * rs2 * g2 + be2;
    ob.z = (zb[2] - mean2) * rs2 * g2 + be2;
    ob.w = (zb[3] - mean2) * rs2 * g2 + be2;
    orow4[f0] = oa;
    orow4[f1] = ob;
}

// ---------------- fallback (strided, self-contained; only if ws too small) ----------------
__global__ __launch_bounds__(NT) void informer_fallback(
    const float* __restrict__ xin,
    const float* __restrict__ gWq, const float* __restrict__ gbq,
    const float* __restrict__ gWk, const float* __restrict__ gbk,
    const float* __restrict__ gWv, const float* __restrict__ gbv,
    const float* __restrict__ gWo, const float* __restrict__ gbo,
    const float* __restrict__ gw1, const float* __restrict__ gb1,
    const float* __restrict__ gw2, const float* __restrict__ gb2,
    const float* __restrict__ gg1, const float* __restrict__ gbe1,
    const float* __restrict__ gg2, const float* __restrict__ gbe2,
    const int* __restrict__ idx,
    float* __restrict__ outp)
{
    const int tid  = threadIdx.x;
    const int lane = tid & 63;
    const int wid  = tid >> 6;
    const int blk  = blockIdx.x;
    const int b    = blk >> 7;
    const int c    = blk & (CC - 1);

    __shared__ float  s_xc[LL];
    __shared__ float  s_kc[LL];
    __shared__ float  s_v[LL];
    __shared__ float  s_red[NW];
    __shared__ double s_cv[NW * UU];
    __shared__ int    s_ci[NW * UU];
    __shared__ int    s_top[UU];
    __shared__ float  s_upd[UU];

    const float Wq = *gWq, bq = *gbq, Wk = *gWk, bk = *gbk;
    const float Wv = *gWv, bv = *gbv, Wo = *gWo, bo = *gbo;
    const float w1 = *gw1, b1 = *gb1, w2 = *gw2, b2 = *gb2;
    const float g1 = *gg1, be1 = *gbe1, g2 = *gg2, be2 = *gbe2;

    const float* xrow = xin + (size_t)b * LL * CC + c;
    float* orow = outp + (size_t)b * LL * CC + c;

    float vsum = 0.f, kmn = 3.4e38f, kmx = -3.4e38f;
    for (int l = tid; l < LL; l += NT) {
        float xv = xrow[(size_t)l * CC];
        s_xc[l] = xv;
        float kvv = __fadd_rn(__fmul_rn(xv, Wk), bk);
        float vvv = __fadd_rn(__fmul_rn(xv, Wv), bv);
        s_kc[l] = kvv;
        s_v[l] = vvv;
        vsum += vvv;
        kmn = fminf(kmn, kvv);
        kmx = fmaxf(kmx, kvv);
    }
    const float vmean  = blockSum(vsum, s_red) * (1.f / (float)LL);
    const float kmxAll = blockMax(kmx, s_red);
    const float kmnAll = blockMin(kmn, s_red);

    double mloc[8];
#pragma unroll
    for (int j = 0; j < 8; ++j) {
        const int l = tid + NT * j;
        const float qv = __fadd_rn(__fmul_rn(s_xc[l], Wq), bq);
        const double qd = (double)qv;
        const int* row = idx + l * UU;
        float kmaxs = -3.4e38f, kmins = 3.4e38f;
        double ssum = 0.0;
#pragma unroll 8
        for (int u = 0; u < UU; ++u) {
            float kvv = s_kc[row[u]];
            kmaxs = fmaxf(kmaxs, kvv);
            kmins = fminf(kmins, kvv);
            ssum += (double)kvv;
        }
        double qmax = (qd >= 0.0) ? qd * (double)kmaxs : qd * (double)kmins;
        mloc[j] = qmax - qd * ssum * (1.0 / (double)LL);
    }

    double wbv = mloc[0]; int wbi = tid;
#pragma unroll
    for (int j = 1; j < 8; ++j)
        if (mloc[j] > wbv) { wbv = mloc[j]; wbi = tid + NT * j; }

    for (int t = 0; t < UU; ++t) {
        double rv = wbv; int ri = wbi;
#pragma unroll
        for (int off = 1; off < 64; off <<= 1) {
            double ov = __shfl_xor(rv, off, 64);
            int    oi = __shfl_xor(ri, off, 64);
            if (ov > rv || (ov == rv && oi < ri)) { rv = ov; ri = oi; }
        }
        if (lane == 0) { s_cv[wid * UU + t] = rv; s_ci[wid * UU + t] = ri; }
        if (wbi == ri) {
#pragma unroll
            for (int j = 0; j < 8; ++j) if ((tid + NT * j) == ri) mloc[j] = -1e300;
            wbv = mloc[0]; wbi = tid;
#pragma unroll
            for (int j = 1; j < 8; ++j)
                if (mloc[j] > wbv) { wbv = mloc[j]; wbi = tid + NT * j; }
        }
    }
    __syncthreads();

    if (wid == 0) {
        double c0v = s_cv[lane], c1v = s_cv[lane + 64];
        int    c0i = s_ci[lane], c1i = s_ci[lane + 64];
        double c2v = (lane < 32) ? s_cv[lane + 128] : -1e300;
        int    c2i = (lane < 32) ? s_ci[lane + 128] : (LL + 1);
        for (int t = 0; t < UU; ++t) {
            double rv = c0v; int ri = c0i;
            if (c1v > rv || (c1v == rv && c1i < ri)) { rv = c1v; ri = c1i; }
            if (c2v > rv || (c2v == rv && c2i < ri)) { rv = c2v; ri = c2i; }
#pragma unroll
            for (int off = 1; off < 64; off <<= 1) {
                double ov = __shfl_xor(rv, off, 64);
                int    oi = __shfl_xor(ri, off, 64);
                if (ov > rv || (ov == rv && oi < ri)) { rv = ov; ri = oi; }
            }
            if (lane == 0) s_top[t] = ri;
            if (c0i == ri) c0v = -1e300;
            else if (c1i == ri) c1v = -1e300;
            else if (c2i == ri) c2v = -1e300;
        }
    }
    __syncthreads();

    for (int r = 0; r < UU / NW; ++r) {
        const int u = r * NW + wid;
        const int p = s_top[u];
        const float qp = __fadd_rn(__fmul_rn(s_xc[p], Wq), bq);
        const float smax = (qp >= 0.f) ? qp * kmxAll : qp * kmnAll;
        float se = 0.f, sev = 0.f;
        for (int l = lane; l < LL; l += 64) {
            float e = __expf(qp * s_kc[l] - smax);
            se += e;
            sev = fmaf(e, s_v[l], sev);
        }
        se = waveSum(se); sev = waveSum(sev);
        if (lane == 0) s_upd[u] = sev / se;
    }
    __syncthreads();

    for (int l = tid; l < LL; l += NT) s_kc[l] = vmean;
    __syncthreads();
    if (tid < UU) s_kc[s_top[tid]] = s_upd[tid];
    __syncthreads();

    float lsum = 0.f;
    for (int l = tid; l < LL; l += NT) {
        float tv = s_xc[l] + __fadd_rn(__fmul_rn(s_kc[l], Wo), bo);
        s_kc[l] = tv;
        lsum += tv;
    }
    const float mean1 = blockSum(lsum, s_red) * (1.f / (float)LL);
    float lss = 0.f;
    for (int l = tid; l < LL; l += NT) { float d = s_kc[l] - mean1; lss += d * d; }
    const float var1 = blockSum(lss, s_red) * (1.f / (float)LL);
    const float rs1 = rsqrtf(var1 + EPSF);

    float lsum2 = 0.f;
    for (int l = tid; l < LL; l += NT) {
        float x1 = (s_kc[l] - mean1) * rs1 * g1 + be1;
        float a  = x1 * w1 + b1;
        float y  = 0.5f * a * (1.f + erff(a * 0.70710678118654752f));
        y = y * w2 + b2;
        float z = x1 + y;
        s_kc[l] = z;
        lsum2 += z;
    }
    const float mean2 = blockSum(lsum2, s_red) * (1.f / (float)LL);
    float lss2 = 0.f;
    for (int l = tid; l < LL; l += NT) { float d = s_kc[l] - mean2; lss2 += d * d; }
    const float var2 = blockSum(lss2, s_red) * (1.f / (float)LL);
    const float rs2 = rsqrtf(var2 + EPSF);

    for (int l = tid; l < LL; l += NT)
        orow[(size_t)l * CC] = (s_kc[l] - mean2) * rs2 * g2 + be2;
}

extern "C" void kernel_launch(void* const* d_in, const int* in_sizes, int n_in,
                              void* d_out, int out_size, void* d_ws, size_t ws_size,
                              hipStream_t stream) {
    const float* x   = (const float*)d_in[0];
    const float* Wq  = (const float*)d_in[1];
    const float* bq  = (const float*)d_in[2];
    const float* Wk  = (const float*)d_in[3];
    const float* bk  = (const float*)d_in[4];
    const float* Wv  = (const float*)d_in[5];
    const float* bv  = (const float*)d_in[6];
    const float* Wo  = (const float*)d_in[7];
    const float* bo  = (const float*)d_in[8];
    const float* w1  = (const float*)d_in[9];
    const float* b1  = (const float*)d_in[10];
    const float* w2  = (const float*)d_in[11];
    const float* b2  = (const float*)d_in[12];
    const float* g1  = (const float*)d_in[13];
    const float* be1 = (const float*)d_in[14];
    const float* g2  = (const float*)d_in[15];
    const float* be2 = (const float*)d_in[16];
    const int*   idx = (const int*)d_in[17];
    float* out = (float*)d_out;

    const size_t SZ = (size_t)BB * LL * CC * sizeof(float);  // 16 MB

    if (ws_size >= 2 * SZ) {
        float* xT = (float*)d_ws;
        float* MT = (float*)((char*)d_ws + SZ);   // becomes outT in-place
        // 1) M[B,L,C] into d_out (coalesced writes; overwritten at the end)
        agg_kernel<<<dim3((LL / 8) * BB), dim3(256), 0, stream>>>(x, idx, Wq, bq, Wk, bk, out);
        // 2) transpose x->xT and M->MT in one launch
        transpose_dual<<<dim3(CC / 32, LL / 32, 2 * BB), dim3(32, 8), 0, stream>>>(x, xT, out, MT);
        // 3) per-row block kernel: topk + u-split softmax + epilogue; writes over MT
        rowBC<<<dim3(BB * CC), dim3(NT), 0, stream>>>(
            xT, MT, Wq, bq, Wk, bk, Wv, bv, Wo, bo, w1, b1, w2, b2,
            g1, be1, g2, be2);
        // 4) transpose back into d_out
        transpose_out<<<dim3(LL / 32, CC / 32, BB), dim3(32, 8), 0, stream>>>(MT, out);
    } else {
        informer_fallback<<<dim3(BB * CC), dim3(NT), 0, stream>>>(
            x, Wq, bq, Wk, bk, Wv, bv, Wo, bo, w1, b1, w2, b2,
            g1, be1, g2, be2, idx, out);
    }
}

// Round 11
// 270.492 us; speedup vs baseline: 1.1083x; 1.1083x over previous
//
#include <hip/hip_runtime.h>
#include <math.h>

#define LL 2048
#define CC 128
#define BB 16
#define UU 40
#define NT 256
#define NW 4
#define EPSF 1e-5f

// ---------------- reduction helpers ----------------
__device__ __forceinline__ float waveSum(float v) {
#pragma unroll
    for (int off = 1; off < 64; off <<= 1) v += __shfl_xor(v, off, 64);
    return v;
}
__device__ __forceinline__ float waveMax(float v) {
#pragma unroll
    for (int off = 1; off < 64; off <<= 1) v = fmaxf(v, __shfl_xor(v, off, 64));
    return v;
}
__device__ __forceinline__ float waveMin(float v) {
#pragma unroll
    for (int off = 1; off < 64; off <<= 1) v = fminf(v, __shfl_xor(v, off, 64));
    return v;
}
__device__ __forceinline__ float blockSum(float v, volatile float* scr) {
    v = waveSum(v);
    const int lane = threadIdx.x & 63, wid = threadIdx.x >> 6;
    __syncthreads();
    if (lane == 0) scr[wid] = v;
    __syncthreads();
    return scr[0] + scr[1] + scr[2] + scr[3];
}
__device__ __forceinline__ float blockMax(float v, volatile float* scr) {
    v = waveMax(v);
    const int lane = threadIdx.x & 63, wid = threadIdx.x >> 6;
    __syncthreads();
    if (lane == 0) scr[wid] = v;
    __syncthreads();
    return fmaxf(fmaxf(scr[0], scr[1]), fmaxf(scr[2], scr[3]));
}
__device__ __forceinline__ float blockMin(float v, volatile float* scr) {
    v = waveMin(v);
    const int lane = threadIdx.x & 63, wid = threadIdx.x >> 6;
    __syncthreads();
    if (lane == 0) scr[wid] = v;
    __syncthreads();
    return fminf(fminf(scr[0], scr[1]), fminf(scr[2], scr[3]));
}

// ---------------- transpose kernels ----------------
__global__ __launch_bounds__(256) void transpose_dual(
    const float* __restrict__ x,  float* __restrict__ xT,
    const float* __restrict__ M,  float* __restrict__ MT) {
    __shared__ float t[32][33];
    const int z  = blockIdx.z;
    const int b  = (z < BB) ? z : (z - BB);
    const float* in  = (z < BB) ? x  : M;
    float* outp      = (z < BB) ? xT : MT;
    const int c0 = blockIdx.x * 32, l0 = blockIdx.y * 32;
    const int lx = threadIdx.x, ly = threadIdx.y;
    const float* base = in + ((size_t)b * LL + l0) * CC + c0;
#pragma unroll
    for (int i = 0; i < 4; ++i) t[ly + i * 8][lx] = base[(size_t)(ly + i * 8) * CC + lx];
    __syncthreads();
    float* obase = outp + ((size_t)b * CC + c0) * LL + l0;
#pragma unroll
    for (int i = 0; i < 4; ++i) obase[(size_t)(ly + i * 8) * LL + lx] = t[lx][ly + i * 8];
}
__global__ __launch_bounds__(256) void transpose_out(const float* __restrict__ in,
                                                     float* __restrict__ outp) {
    __shared__ float t[32][33];
    const int b  = blockIdx.z;
    const int l0 = blockIdx.x * 32, c0 = blockIdx.y * 32;
    const int lx = threadIdx.x, ly = threadIdx.y;
    const float* base = in + ((size_t)b * CC + c0) * LL + l0;
#pragma unroll
    for (int i = 0; i < 4; ++i) t[ly + i * 8][lx] = base[(size_t)(ly + i * 8) * LL + lx];
    __syncthreads();
    float* obase = outp + ((size_t)b * LL + l0) * CC + c0;
#pragma unroll
    for (int i = 0; i < 4; ++i) obase[(size_t)(ly + i * 8) * CC + lx] = t[lx][ly + i * 8];
}

// ---------------- M aggregate kernel (R5-proven, XCD-swizzled) ----------------
__global__ __launch_bounds__(256) void agg_kernel(
    const float* __restrict__ x, const int* __restrict__ idx,
    const float* __restrict__ gWq, const float* __restrict__ gbq,
    const float* __restrict__ gWk, const float* __restrict__ gbk,
    float* __restrict__ M)
{
    __shared__ int s_idx[8 * UU];
    const int tid = threadIdx.x;
    const int g   = blockIdx.x;
    const int b   = ((g & 7) << 1) | ((g >> 3) & 1);
    const int l0  = (g >> 4) * 8;
    if (tid < 256)          s_idx[tid]       = idx[l0 * UU + tid];
    if (tid < 8 * UU - 256) s_idx[256 + tid] = idx[l0 * UU + 256 + tid];
    __syncthreads();

    const int s = tid & 31;       // c-quad: c = 4s..4s+3
    const int r = tid >> 5;       // row slot
    const int l = l0 + r;
    const float Wq = *gWq, bq = *gbq, Wk = *gWk, bk = *gbk;

    const float4* xb = (const float4*)(x + (size_t)b * LL * CC);
    float4 xo4 = xb[(size_t)l * 32 + s];
    float xo[4] = {xo4.x, xo4.y, xo4.z, xo4.w};

    float  mx[4] = {-3.4e38f, -3.4e38f, -3.4e38f, -3.4e38f};
    float  mn[4] = { 3.4e38f,  3.4e38f,  3.4e38f,  3.4e38f};
    double sm[4] = {0.0, 0.0, 0.0, 0.0};
    const int* rowp = &s_idx[r * UU];
#pragma unroll 8
    for (int u = 0; u < UU; ++u) {
        const int i = rowp[u];
        float4 xv = xb[(size_t)i * 32 + s];
        float xa[4] = {xv.x, xv.y, xv.z, xv.w};
#pragma unroll
        for (int t = 0; t < 4; ++t) {
            mx[t] = fmaxf(mx[t], xa[t]);
            mn[t] = fminf(mn[t], xa[t]);
            sm[t] += (double)xa[t];
        }
    }
    float mo[4];
#pragma unroll
    for (int t = 0; t < 4; ++t) {
        const float xH = (Wk >= 0.f) ? mx[t] : mn[t];
        const float xL = (Wk >= 0.f) ? mn[t] : mx[t];
        const float kH = __fadd_rn(__fmul_rn(xH, Wk), bk);   // = max_u k, bit-exact
        const float kL = __fadd_rn(__fmul_rn(xL, Wk), bk);   // = min_u k, bit-exact
        const float q  = __fadd_rn(__fmul_rn(xo[t], Wq), bq);
        const float t1 = __fmul_rn(q, (q >= 0.f) ? kH : kL); // = max_u f32(q*k_u)
        const double ks = (double)Wk * sm[t] + 40.0 * (double)bk;
        const float t2 = (float)(((double)q * ks) * (1.0 / 2048.0));
        mo[t] = __fsub_rn(t1, t2);
    }
    float4 Mo = make_float4(mo[0], mo[1], mo[2], mo[3]);
    ((float4*)(M + ((size_t)b * LL + l) * CC))[s] = Mo;
}

// insert (val,idxl) into sorted-4 cache (v0 best; tie -> lower index)
#define TOP4_INSERT(val, idxl)                                                  \
    {                                                                           \
        const bool b0 = (val) > cv0 || ((val) == cv0 && (idxl) < ci0);          \
        const bool b1 = (val) > cv1 || ((val) == cv1 && (idxl) < ci1);          \
        const bool b2 = (val) > cv2 || ((val) == cv2 && (idxl) < ci2);          \
        const bool b3 = (val) > cv3 || ((val) == cv3 && (idxl) < ci3);          \
        if (b0)      { cv3=cv2;ci3=ci2; cv2=cv1;ci2=ci1; cv1=cv0;ci1=ci0; cv0=(val);ci0=(idxl); } \
        else if (b1) { cv3=cv2;ci3=ci2; cv2=cv1;ci2=ci1; cv1=(val);ci1=(idxl); } \
        else if (b2) { cv3=cv2;ci3=ci2; cv2=(val);ci2=(idxl); }                 \
        else if (b3) { cv3=(val);ci3=(idxl); }                                  \
    }

// ---------------- rowBC: block per row; wave0 cheap top-40; u-split softmax ----------------
__global__ __launch_bounds__(NT) void rowBC(
    const float* __restrict__ xT,    // [B,C,L]
    float* MoT,                      // [B,C,L] in: M, out: result (row-exclusive)
    const float* __restrict__ gWq, const float* __restrict__ gbq,
    const float* __restrict__ gWk, const float* __restrict__ gbk,
    const float* __restrict__ gWv, const float* __restrict__ gbv,
    const float* __restrict__ gWo, const float* __restrict__ gbo,
    const float* __restrict__ gw1, const float* __restrict__ gb1,
    const float* __restrict__ gw2, const float* __restrict__ gb2,
    const float* __restrict__ gg1, const float* __restrict__ gbe1,
    const float* __restrict__ gg2, const float* __restrict__ gbe2)
{
    const int tid = threadIdx.x;
    const int ln  = tid & 63;
    const int wid = tid >> 6;
    const int r   = blockIdx.x;      // row = b*CC + c

    __shared__ __align__(16) float s_ctx[LL];
    __shared__ int   s_top[UU];
    __shared__ float s_red[NW];

    const float Wq = *gWq, bq = *gbq, Wk = *gWk, bk = *gbk;
    const float Wv = *gWv, bv = *gbv, Wo = *gWo, bo = *gbo;
    const float w1 = *gw1, b1 = *gb1, w2 = *gw2, b2 = *gb2;
    const float g1 = *gg1, be1 = *gbe1, g2 = *gg2, be2 = *gbe2;
    const float LOG2E = 1.4426950408889634f;

    const float*  xrow  = xT + (size_t)r * LL;
    const float4* xrow4 = (const float4*)xrow;
    float* Mrow = MoT + (size_t)r * LL;
    const float4* mrow4 = (const float4*)Mrow;
    float4* orow4 = (float4*)Mrow;
    float4* ctx4  = (float4*)s_ctx;

    // ---- 1: top-40 — WAVE 0 ONLY (per-lane sorted top-4 cache + consume mask)
    if (wid == 0) {
        float cv0 = -3.4e38f, cv1 = -3.4e38f, cv2 = -3.4e38f, cv3 = -3.4e38f;
        int   ci0 = LL + 1,   ci1 = LL + 1,   ci2 = LL + 1,   ci3 = LL + 1;
        {
            // build from M row; mv dies after this scope (rebuild re-loads from L2)
#pragma unroll
            for (int m = 0; m < 8; ++m) {
                float4 w = mrow4[ln + m * 64];
                const int l0 = 4 * (ln + 64 * m);
                TOP4_INSERT(w.x, l0);
                TOP4_INSERT(w.y, l0 + 1);
                TOP4_INSERT(w.z, l0 + 2);
                TOP4_INSERT(w.w, l0 + 3);
            }
        }
        unsigned int consumed = 0u;
        for (int t = 0; t < UU; ++t) {
            float rv = cv0; int ri = ci0;
#pragma unroll
            for (int off = 1; off < 64; off <<= 1) {
                float ov = __shfl_xor(rv, off, 64);
                int   oi = __shfl_xor(ri, off, 64);
                if (ov > rv || (ov == rv && oi < ri)) { rv = ov; ri = oi; }
            }
            if (ln == 0) s_top[t] = ri;
            if (ci0 == ri) {                      // owner: consume + shift cache
                const int qq = ri & 3;
                const int mm = ((ri >> 2) - ln) >> 6;
                consumed |= (1u << (4 * mm + qq));
                cv0 = cv1; ci0 = ci1; cv1 = cv2; ci1 = ci2;
                cv2 = cv3; ci2 = ci3; cv3 = -3.4e38f; ci3 = LL + 1;
                if (ci0 == LL + 1) {              // cache empty: exact rebuild (rare)
                    cv0 = cv1 = cv2 = cv3 = -3.4e38f;
                    ci0 = ci1 = ci2 = ci3 = LL + 1;
#pragma unroll
                    for (int m = 0; m < 8; ++m) {
                        float4 w = mrow4[ln + m * 64];
                        const int l0 = 4 * (ln + 64 * m);
                        if (!(consumed & (1u << (4 * m + 0)))) TOP4_INSERT(w.x, l0);
                        if (!(consumed & (1u << (4 * m + 1)))) TOP4_INSERT(w.y, l0 + 1);
                        if (!(consumed & (1u << (4 * m + 2)))) TOP4_INSERT(w.z, l0 + 2);
                        if (!(consumed & (1u << (4 * m + 3)))) TOP4_INSERT(w.w, l0 + 3);
                    }
                }
            }
        }
    }

    // ---- 2: load x row (per wave); stats via monotone affine of x
    float4 xc[8];
    float vsum = 0.f, xmx = -3.4e38f, xmn = 3.4e38f;
#pragma unroll
    for (int m = 0; m < 8; ++m) {
        float4 xv = xrow4[ln + m * 64];
        xc[m] = xv;
        vsum += __fadd_rn(__fmul_rn(xv.x, Wv), bv) + __fadd_rn(__fmul_rn(xv.y, Wv), bv)
              + __fadd_rn(__fmul_rn(xv.z, Wv), bv) + __fadd_rn(__fmul_rn(xv.w, Wv), bv);
        xmx = fmaxf(xmx, fmaxf(fmaxf(xv.x, xv.y), fmaxf(xv.z, xv.w)));
        xmn = fminf(xmn, fminf(fminf(xv.x, xv.y), fminf(xv.z, xv.w)));
    }
    vsum = waveSum(vsum);
    xmx  = waveMax(xmx);
    xmn  = waveMin(xmn);
    const float vmean = vsum * (1.f / (float)LL);
    const float kmx = __fadd_rn(__fmul_rn((Wk >= 0.f) ? xmx : xmn, Wk), bk);
    const float kmn = __fadd_rn(__fmul_rn((Wk >= 0.f) ? xmn : xmx, Wk), bk);

    // ---- 3: init ctx (each wave its quarter)
    const float4 vm4 = make_float4(vmean, vmean, vmean, vmean);
    ctx4[128 * wid + ln]      = vm4;
    ctx4[128 * wid + 64 + ln] = vm4;
    __syncthreads();   // s_top + ctx visible to all

    // ---- 4: softmax, wave owns u = 10*wid .. 10*wid+9, two groups of 5.
    // e = exp2(A*x + B), A = qp*Wk*log2e, B = (qp*bk - smax)*log2e
#pragma unroll
    for (int g = 0; g < 2; ++g) {
        int p[5]; float A[5], Bc[5];
#pragma unroll
        for (int q = 0; q < 5; ++q) {
            p[q] = s_top[wid * 10 + g * 5 + q];
            const float xq = xrow[p[q]];
            const float qp = __fadd_rn(__fmul_rn(xq, Wq), bq);
            const float sm = (qp >= 0.f) ? __fmul_rn(qp, kmx) : __fmul_rn(qp, kmn);
            A[q]  = qp * Wk * LOG2E;
            Bc[q] = (qp * bk - sm) * LOG2E;
        }
        float se[5] = {0.f, 0.f, 0.f, 0.f, 0.f};
        float sx[5] = {0.f, 0.f, 0.f, 0.f, 0.f};
#pragma unroll
        for (int m = 0; m < 8; ++m) {
            float4 x4 = xc[m];
#pragma unroll
            for (int q = 0; q < 5; ++q) {
                float e;
                e = exp2f(fmaf(A[q], x4.x, Bc[q])); se[q] += e; sx[q] = fmaf(e, x4.x, sx[q]);
                e = exp2f(fmaf(A[q], x4.y, Bc[q])); se[q] += e; sx[q] = fmaf(e, x4.y, sx[q]);
                e = exp2f(fmaf(A[q], x4.z, Bc[q])); se[q] += e; sx[q] = fmaf(e, x4.z, sx[q]);
                e = exp2f(fmaf(A[q], x4.w, Bc[q])); se[q] += e; sx[q] = fmaf(e, x4.w, sx[q]);
            }
        }
#pragma unroll
        for (int q = 0; q < 5; ++q) {
            const float seA = waveSum(se[q]);
            const float sxA = waveSum(sx[q]);
            const float upd = (Wv * sxA + bv * seA) / seA;   // Σe·v = Wv·Σe·x + bv·Σe
            if (ln == 0) s_ctx[p[q]] = upd;
        }
    }
    __syncthreads();

    // ---- 5: epilogue, each wave its quarter (static indices; x from xc is gone
    // for other quarters, so re-read the two needed float4 from L2)
    const int f0 = 128 * wid + ln, f1 = f0 + 64;
    float4 xa = xrow4[f0], xb2 = xrow4[f1];
    float4 ca = ctx4[f0],  cb = ctx4[f1];
    float4 ta, tb;
    ta.x = xa.x + __fadd_rn(__fmul_rn(ca.x, Wo), bo);
    ta.y = xa.y + __fadd_rn(__fmul_rn(ca.y, Wo), bo);
    ta.z = xa.z + __fadd_rn(__fmul_rn(ca.z, Wo), bo);
    ta.w = xa.w + __fadd_rn(__fmul_rn(ca.w, Wo), bo);
    tb.x = xb2.x + __fadd_rn(__fmul_rn(cb.x, Wo), bo);
    tb.y = xb2.y + __fadd_rn(__fmul_rn(cb.y, Wo), bo);
    tb.z = xb2.z + __fadd_rn(__fmul_rn(cb.z, Wo), bo);
    tb.w = xb2.w + __fadd_rn(__fmul_rn(cb.w, Wo), bo);
    float lsum = ta.x + ta.y + ta.z + ta.w + tb.x + tb.y + tb.z + tb.w;
    const float mean1 = blockSum(lsum, s_red) * (1.f / (float)LL);
    float lss = 0.f;
    {
        float d0 = ta.x - mean1, d1 = ta.y - mean1, d2 = ta.z - mean1, d3 = ta.w - mean1;
        float d4 = tb.x - mean1, d5 = tb.y - mean1, d6 = tb.z - mean1, d7 = tb.w - mean1;
        lss = d0*d0 + d1*d1 + d2*d2 + d3*d3 + d4*d4 + d5*d5 + d6*d6 + d7*d7;
    }
    const float var1 = blockSum(lss, s_red) * (1.f / (float)LL);
    const float rs1 = rsqrtf(var1 + EPSF);

    float za[4], zb[4];
    {
        const float tin[8] = {ta.x, ta.y, ta.z, ta.w, tb.x, tb.y, tb.z, tb.w};
        float zo[8];
#pragma unroll
        for (int e = 0; e < 8; ++e) {
            float x1 = (tin[e] - mean1) * rs1 * g1 + be1;
            float a  = x1 * w1 + b1;
            float y  = 0.5f * a * (1.f + erff(a * 0.70710678118654752f));
            zo[e] = x1 + (y * w2 + b2);
        }
        za[0] = zo[0]; za[1] = zo[1]; za[2] = zo[2]; za[3] = zo[3];
        zb[0] = zo[4]; zb[1] = zo[5]; zb[2] = zo[6]; zb[3] = zo[7];
    }
    float lsum2 = za[0] + za[1] + za[2] + za[3] + zb[0] + zb[1] + zb[2] + zb[3];
    const float mean2 = blockSum(lsum2, s_red) * (1.f / (float)LL);
    float lss2 = 0.f;
#pragma unroll
    for (int e = 0; e < 4; ++e) {
        float d0 = za[e] - mean2, d1 = zb[e] - mean2;
        lss2 += d0 * d0 + d1 * d1;
    }
    const float var2 = blockSum(lss2, s_red) * (1.f / (float)LL);
    const float rs2 = rsqrtf(var2 + EPSF);

    float4 oa, ob;
    oa.x = (za[0] - mean2) * rs2 * g2 + be2;
    oa.y = (za[1] - mean2) * rs2 * g2 + be2;
    oa.z = (za[2] - mean2) * rs2 * g2 + be2;
    oa.w = (za[3] - mean2) * rs2 * g2 + be2;
    ob.x = (zb[0] - mean2) * rs2 * g2 + be2;
    ob.y = (zb[1] - mean2) * rs2 * g2 + be2;
    ob.z = (zb[2] - mean2) * rs2 * g2 + be2;
    ob.w = (zb[3] - mean2) * rs2 * g2 + be2;
    orow4[f0] = oa;
    orow4[f1] = ob;
}

// ---------------- fallback (strided, self-contained; only if ws too small) ----------------
__global__ __launch_bounds__(NT) void informer_fallback(
    const float* __restrict__ xin,
    const float* __restrict__ gWq, const float* __restrict__ gbq,
    const float* __restrict__ gWk, const float* __restrict__ gbk,
    const float* __restrict__ gWv, const float* __restrict__ gbv,
    const float* __restrict__ gWo, const float* __restrict__ gbo,
    const float* __restrict__ gw1, const float* __restrict__ gb1,
    const float* __restrict__ gw2, const float* __restrict__ gb2,
    const float* __restrict__ gg1, const float* __restrict__ gbe1,
    const float* __restrict__ gg2, const float* __restrict__ gbe2,
    const int* __restrict__ idx,
    float* __restrict__ outp)
{
    const int tid  = threadIdx.x;
    const int lane = tid & 63;
    const int wid  = tid >> 6;
    const int blk  = blockIdx.x;
    const int b    = blk >> 7;
    const int c    = blk & (CC - 1);

    __shared__ float  s_xc[LL];
    __shared__ float  s_kc[LL];
    __shared__ float  s_v[LL];
    __shared__ float  s_red[NW];
    __shared__ double s_cv[NW * UU];
    __shared__ int    s_ci[NW * UU];
    __shared__ int    s_top[UU];
    __shared__ float  s_upd[UU];

    const float Wq = *gWq, bq = *gbq, Wk = *gWk, bk = *gbk;
    const float Wv = *gWv, bv = *gbv, Wo = *gWo, bo = *gbo;
    const float w1 = *gw1, b1 = *gb1, w2 = *gw2, b2 = *gb2;
    const float g1 = *gg1, be1 = *gbe1, g2 = *gg2, be2 = *gbe2;

    const float* xrow = xin + (size_t)b * LL * CC + c;
    float* orow = outp + (size_t)b * LL * CC + c;

    float vsum = 0.f, kmn = 3.4e38f, kmx = -3.4e38f;
    for (int l = tid; l < LL; l += NT) {
        float xv = xrow[(size_t)l * CC];
        s_xc[l] = xv;
        float kvv = __fadd_rn(__fmul_rn(xv, Wk), bk);
        float vvv = __fadd_rn(__fmul_rn(xv, Wv), bv);
        s_kc[l] = kvv;
        s_v[l] = vvv;
        vsum += vvv;
        kmn = fminf(kmn, kvv);
        kmx = fmaxf(kmx, kvv);
    }
    const float vmean  = blockSum(vsum, s_red) * (1.f / (float)LL);
    const float kmxAll = blockMax(kmx, s_red);
    const float kmnAll = blockMin(kmn, s_red);

    double mloc[8];
#pragma unroll
    for (int j = 0; j < 8; ++j) {
        const int l = tid + NT * j;
        const float qv = __fadd_rn(__fmul_rn(s_xc[l], Wq), bq);
        const double qd = (double)qv;
        const int* row = idx + l * UU;
        float kmaxs = -3.4e38f, kmins = 3.4e38f;
        double ssum = 0.0;
#pragma unroll 8
        for (int u = 0; u < UU; ++u) {
            float kvv = s_kc[row[u]];
            kmaxs = fmaxf(kmaxs, kvv);
            kmins = fminf(kmins, kvv);
            ssum += (double)kvv;
        }
        double qmax = (qd >= 0.0) ? qd * (double)kmaxs : qd * (double)kmins;
        mloc[j] = qmax - qd * ssum * (1.0 / (double)LL);
    }

    double wbv = mloc[0]; int wbi = tid;
#pragma unroll
    for (int j = 1; j < 8; ++j)
        if (mloc[j] > wbv) { wbv = mloc[j]; wbi = tid + NT * j; }

    for (int t = 0; t < UU; ++t) {
        double rv = wbv; int ri = wbi;
#pragma unroll
        for (int off = 1; off < 64; off <<= 1) {
            double ov = __shfl_xor(rv, off, 64);
            int    oi = __shfl_xor(ri, off, 64);
            if (ov > rv || (ov == rv && oi < ri)) { rv = ov; ri = oi; }
        }
        if (lane == 0) { s_cv[wid * UU + t] = rv; s_ci[wid * UU + t] = ri; }
        if (wbi == ri) {
#pragma unroll
            for (int j = 0; j < 8; ++j) if ((tid + NT * j) == ri) mloc[j] = -1e300;
            wbv = mloc[0]; wbi = tid;
#pragma unroll
            for (int j = 1; j < 8; ++j)
                if (mloc[j] > wbv) { wbv = mloc[j]; wbi = tid + NT * j; }
        }
    }
    __syncthreads();

    if (wid == 0) {
        double c0v = s_cv[lane], c1v = s_cv[lane + 64];
        int    c0i = s_ci[lane], c1i = s_ci[lane + 64];
        double c2v = (lane < 32) ? s_cv[lane + 128] : -1e300;
        int    c2i = (lane < 32) ? s_ci[lane + 128] : (LL + 1);
        for (int t = 0; t < UU; ++t) {
            double rv = c0v; int ri = c0i;
            if (c1v > rv || (c1v == rv && c1i < ri)) { rv = c1v; ri = c1i; }
            if (c2v > rv || (c2v == rv && c2i < ri)) { rv = c2v; ri = c2i; }
#pragma unroll
            for (int off = 1; off < 64; off <<= 1) {
                double ov = __shfl_xor(rv, off, 64);
                int    oi = __shfl_xor(ri, off, 64);
                if (ov > rv || (ov == rv && oi < ri)) { rv = ov; ri = oi; }
            }
            if (lane == 0) s_top[t] = ri;
            if (c0i == ri) c0v = -1e300;
            else if (c1i == ri) c1v = -1e300;
            else if (c2i == ri) c2v = -1e300;
        }
    }
    __syncthreads();

    for (int r = 0; r < UU / NW; ++r) {
        const int u = r * NW + wid;
        const int p = s_top[u];
        const float qp = __fadd_rn(__fmul_rn(s_xc[p], Wq), bq);
        const float smax = (qp >= 0.f) ? qp * kmxAll : qp * kmnAll;
        float se = 0.f, sev = 0.f;
        for (int l = lane; l < LL; l += 64) {
            float e = __expf(qp * s_kc[l] - smax);
            se += e;
            sev = fmaf(e, s_v[l], sev);
        }
        se = waveSum(se); sev = waveSum(sev);
        if (lane == 0) s_upd[u] = sev / se;
    }
    __syncthreads();

    for (int l = tid; l < LL; l += NT) s_kc[l] = vmean;
    __syncthreads();
    if (tid < UU) s_kc[s_top[tid]] = s_upd[tid];
    __syncthreads();

    float lsum = 0.f;
    for (int l = tid; l < LL; l += NT) {
        float tv = s_xc[l] + __fadd_rn(__fmul_rn(s_kc[l], Wo), bo);
        s_kc[l] = tv;
        lsum += tv;
    }
    const float mean1 = blockSum(lsum, s_red) * (1.f / (float)LL);
    float lss = 0.f;
    for (int l = tid; l < LL; l += NT) { float d = s_kc[l] - mean1; lss += d * d; }
    const float var1 = blockSum(lss, s_red) * (1.f / (float)LL);
    const float rs1 = rsqrtf(var1 + EPSF);

    float lsum2 = 0.f;
    for (int l = tid; l < LL; l += NT) {
        float x1 = (s_kc[l] - mean1) * rs1 * g1 + be1;
        float a  = x1 * w1 + b1;
        float y  = 0.5f * a * (1.f + erff(a * 0.70710678118654752f));
        y = y * w2 + b2;
        float z = x1 + y;
        s_kc[l] = z;
        lsum2 += z;
    }
    const float mean2 = blockSum(lsum2, s_red) * (1.f / (float)LL);
    float lss2 = 0.f;
    for (int l = tid; l < LL; l += NT) { float d = s_kc[l] - mean2; lss2 += d * d; }
    const float var2 = blockSum(lss2, s_red) * (1.f / (float)LL);
    const float rs2 = rsqrtf(var2 + EPSF);

    for (int l = tid; l < LL; l += NT)
        orow[(size_t)l * CC] = (s_kc[l] - mean2) * rs2 * g2 + be2;
}

extern "C" void kernel_launch(void* const* d_in, const int* in_sizes, int n_in,
                              void* d_out, int out_size, void* d_ws, size_t ws_size,
                              hipStream_t stream) {
    const float* x   = (const float*)d_in[0];
    const float* Wq  = (const float*)d_in[1];
    const float* bq  = (const float*)d_in[2];
    const float* Wk  = (const float*)d_in[3];
    const float* bk  = (const float*)d_in[4];
    const float* Wv  = (const float*)d_in[5];
    const float* bv  = (const float*)d_in[6];
    const float* Wo  = (const float*)d_in[7];
    const float* bo  = (const float*)d_in[8];
    const float* w1  = (const float*)d_in[9];
    const float* b1  = (const float*)d_in[10];
    const float* w2  = (const float*)d_in[11];
    const float* b2  = (const float*)d_in[12];
    const float* g1  = (const float*)d_in[13];
    const float* be1 = (const float*)d_in[14];
    const float* g2  = (const float*)d_in[15];
    const float* be2 = (const float*)d_in[16];
    const int*   idx = (const int*)d_in[17];
    float* out = (float*)d_out;

    const size_t SZ = (size_t)BB * LL * CC * sizeof(float);  // 16 MB

    if (ws_size >= 2 * SZ) {
        float* xT = (float*)d_ws;
        float* MT = (float*)((char*)d_ws + SZ);   // becomes outT in-place
        // 1) M[B,L,C] into d_out (coalesced writes; overwritten at the end)
        agg_kernel<<<dim3((LL / 8) * BB), dim3(256), 0, stream>>>(x, idx, Wq, bq, Wk, bk, out);
        // 2) transpose x->xT and M->MT in one launch
        transpose_dual<<<dim3(CC / 32, LL / 32, 2 * BB), dim3(32, 8), 0, stream>>>(x, xT, out, MT);
        // 3) block-per-row: wave0 top-40 + u-split softmax + epilogue; writes over MT
        rowBC<<<dim3(BB * CC), dim3(NT), 0, stream>>>(
            xT, MT, Wq, bq, Wk, bk, Wv, bv, Wo, bo, w1, b1, w2, b2,
            g1, be1, g2, be2);
        // 4) transpose back into d_out
        transpose_out<<<dim3(LL / 32, CC / 32, BB), dim3(32, 8), 0, stream>>>(MT, out);
    } else {
        informer_fallback<<<dim3(BB * CC), dim3(NT), 0, stream>>>(
            x, Wq, bq, Wk, bk, Wv, bv, Wo, bo, w1, b1, w2, b2,
            g1, be1, g2, be2, idx, out);
    }
}

// Round 12
// 248.212 us; speedup vs baseline: 1.2077x; 1.0898x over previous
//
#include <hip/hip_runtime.h>
#include <math.h>

#define LL 2048
#define CC 128
#define BB 16
#define UU 40
#define NT 256
#define NW 4
#define EPSF 1e-5f

// ---------------- reduction helpers ----------------
__device__ __forceinline__ float waveSum(float v) {
#pragma unroll
    for (int off = 1; off < 64; off <<= 1) v += __shfl_xor(v, off, 64);
    return v;
}
__device__ __forceinline__ float waveMax(float v) {
#pragma unroll
    for (int off = 1; off < 64; off <<= 1) v = fmaxf(v, __shfl_xor(v, off, 64));
    return v;
}
__device__ __forceinline__ float waveMin(float v) {
#pragma unroll
    for (int off = 1; off < 64; off <<= 1) v = fminf(v, __shfl_xor(v, off, 64));
    return v;
}
__device__ __forceinline__ float blockSum(float v, volatile float* scr) {
    v = waveSum(v);
    const int lane = threadIdx.x & 63, wid = threadIdx.x >> 6;
    __syncthreads();
    if (lane == 0) scr[wid] = v;
    __syncthreads();
    return scr[0] + scr[1] + scr[2] + scr[3];
}
__device__ __forceinline__ float blockMax(float v, volatile float* scr) {
    v = waveMax(v);
    const int lane = threadIdx.x & 63, wid = threadIdx.x >> 6;
    __syncthreads();
    if (lane == 0) scr[wid] = v;
    __syncthreads();
    return fmaxf(fmaxf(scr[0], scr[1]), fmaxf(scr[2], scr[3]));
}
__device__ __forceinline__ float blockMin(float v, volatile float* scr) {
    v = waveMin(v);
    const int lane = threadIdx.x & 63, wid = threadIdx.x >> 6;
    __syncthreads();
    if (lane == 0) scr[wid] = v;
    __syncthreads();
    return fminf(fminf(scr[0], scr[1]), fminf(scr[2], scr[3]));
}

// ---------------- transpose kernels ----------------
__global__ __launch_bounds__(256) void transpose_dual(
    const float* __restrict__ x,  float* __restrict__ xT,
    const float* __restrict__ M,  float* __restrict__ MT) {
    __shared__ float t[32][33];
    const int z  = blockIdx.z;
    const int b  = (z < BB) ? z : (z - BB);
    const float* in  = (z < BB) ? x  : M;
    float* outp      = (z < BB) ? xT : MT;
    const int c0 = blockIdx.x * 32, l0 = blockIdx.y * 32;
    const int lx = threadIdx.x, ly = threadIdx.y;
    const float* base = in + ((size_t)b * LL + l0) * CC + c0;
#pragma unroll
    for (int i = 0; i < 4; ++i) t[ly + i * 8][lx] = base[(size_t)(ly + i * 8) * CC + lx];
    __syncthreads();
    float* obase = outp + ((size_t)b * CC + c0) * LL + l0;
#pragma unroll
    for (int i = 0; i < 4; ++i) obase[(size_t)(ly + i * 8) * LL + lx] = t[lx][ly + i * 8];
}
__global__ __launch_bounds__(256) void transpose_out(const float* __restrict__ in,
                                                     float* __restrict__ outp) {
    __shared__ float t[32][33];
    const int b  = blockIdx.z;
    const int l0 = blockIdx.x * 32, c0 = blockIdx.y * 32;
    const int lx = threadIdx.x, ly = threadIdx.y;
    const float* base = in + ((size_t)b * CC + c0) * LL + l0;
#pragma unroll
    for (int i = 0; i < 4; ++i) t[ly + i * 8][lx] = base[(size_t)(ly + i * 8) * LL + lx];
    __syncthreads();
    float* obase = outp + ((size_t)b * LL + l0) * CC + c0;
#pragma unroll
    for (int i = 0; i < 4; ++i) obase[(size_t)(ly + i * 8) * CC + lx] = t[lx][ly + i * 8];
}

// ---------------- M aggregate kernel (R5-proven, XCD-swizzled) ----------------
__global__ __launch_bounds__(256) void agg_kernel(
    const float* __restrict__ x, const int* __restrict__ idx,
    const float* __restrict__ gWq, const float* __restrict__ gbq,
    const float* __restrict__ gWk, const float* __restrict__ gbk,
    float* __restrict__ M)
{
    __shared__ int s_idx[8 * UU];
    const int tid = threadIdx.x;
    const int g   = blockIdx.x;
    const int b   = ((g & 7) << 1) | ((g >> 3) & 1);
    const int l0  = (g >> 4) * 8;
    if (tid < 256)          s_idx[tid]       = idx[l0 * UU + tid];
    if (tid < 8 * UU - 256) s_idx[256 + tid] = idx[l0 * UU + 256 + tid];
    __syncthreads();

    const int s = tid & 31;       // c-quad: c = 4s..4s+3
    const int r = tid >> 5;       // row slot
    const int l = l0 + r;
    const float Wq = *gWq, bq = *gbq, Wk = *gWk, bk = *gbk;

    const float4* xb = (const float4*)(x + (size_t)b * LL * CC);
    float4 xo4 = xb[(size_t)l * 32 + s];
    float xo[4] = {xo4.x, xo4.y, xo4.z, xo4.w};

    float  mx[4] = {-3.4e38f, -3.4e38f, -3.4e38f, -3.4e38f};
    float  mn[4] = { 3.4e38f,  3.4e38f,  3.4e38f,  3.4e38f};
    double sm[4] = {0.0, 0.0, 0.0, 0.0};
    const int* rowp = &s_idx[r * UU];
#pragma unroll 8
    for (int u = 0; u < UU; ++u) {
        const int i = rowp[u];
        float4 xv = xb[(size_t)i * 32 + s];
        float xa[4] = {xv.x, xv.y, xv.z, xv.w};
#pragma unroll
        for (int t = 0; t < 4; ++t) {
            mx[t] = fmaxf(mx[t], xa[t]);
            mn[t] = fminf(mn[t], xa[t]);
            sm[t] += (double)xa[t];
        }
    }
    float mo[4];
#pragma unroll
    for (int t = 0; t < 4; ++t) {
        const float xH = (Wk >= 0.f) ? mx[t] : mn[t];
        const float xL = (Wk >= 0.f) ? mn[t] : mx[t];
        const float kH = __fadd_rn(__fmul_rn(xH, Wk), bk);   // = max_u k, bit-exact
        const float kL = __fadd_rn(__fmul_rn(xL, Wk), bk);   // = min_u k, bit-exact
        const float q  = __fadd_rn(__fmul_rn(xo[t], Wq), bq);
        const float t1 = __fmul_rn(q, (q >= 0.f) ? kH : kL); // = max_u f32(q*k_u)
        const double ks = (double)Wk * sm[t] + 40.0 * (double)bk;
        const float t2 = (float)(((double)q * ks) * (1.0 / 2048.0));
        mo[t] = __fsub_rn(t1, t2);
    }
    float4 Mo = make_float4(mo[0], mo[1], mo[2], mo[3]);
    ((float4*)(M + ((size_t)b * LL + l) * CC))[s] = Mo;
}

// insert (val,idxl) into sorted-4 cache (v0 best; tie -> lower index)
#define TOP4_INSERT(val, idxl)                                                  \
    {                                                                           \
        const bool b0 = (val) > cv0 || ((val) == cv0 && (idxl) < ci0);          \
        const bool b1 = (val) > cv1 || ((val) == cv1 && (idxl) < ci1);          \
        const bool b2 = (val) > cv2 || ((val) == cv2 && (idxl) < ci2);          \
        const bool b3 = (val) > cv3 || ((val) == cv3 && (idxl) < ci3);          \
        if (b0)      { cv3=cv2;ci3=ci2; cv2=cv1;ci2=ci1; cv1=cv0;ci1=ci0; cv0=(val);ci0=(idxl); } \
        else if (b1) { cv3=cv2;ci3=ci2; cv2=cv1;ci2=ci1; cv1=(val);ci1=(idxl); } \
        else if (b2) { cv3=cv2;ci3=ci2; cv2=(val);ci2=(idxl); }                 \
        else if (b3) { cv3=(val);ci3=(idxl); }                                  \
    }

// ---------------- rowBC: ONE WAVE PER ROW (R9 shell), cheap top-40, exp2 softmax ----------------
// MoT [B,C,L]: holds MT on entry; each wave overwrites its own row with output.
// No block barriers anywhere.
__global__ __launch_bounds__(NT) void rowBC(
    const float* __restrict__ xT,    // [B,C,L]
    float* MoT,                      // [B,C,L] in: M, out: result (row-exclusive)
    const float* __restrict__ gWq, const float* __restrict__ gbq,
    const float* __restrict__ gWk, const float* __restrict__ gbk,
    const float* __restrict__ gWv, const float* __restrict__ gbv,
    const float* __restrict__ gWo, const float* __restrict__ gbo,
    const float* __restrict__ gw1, const float* __restrict__ gb1,
    const float* __restrict__ gw2, const float* __restrict__ gb2,
    const float* __restrict__ gg1, const float* __restrict__ gbe1,
    const float* __restrict__ gg2, const float* __restrict__ gbe2)
{
    const int tid = threadIdx.x;
    const int ln  = tid & 63;
    const int wid = tid >> 6;
    const int r   = blockIdx.x * 4 + wid;   // row = b*CC + c

    __shared__ __align__(16) float s_ctx[4][LL];
    __shared__ int s_top[4][UU];

    const float Wq = *gWq, bq = *gbq, Wk = *gWk, bk = *gbk;
    const float Wv = *gWv, bv = *gbv, Wo = *gWo, bo = *gbo;
    const float w1 = *gw1, b1 = *gb1, w2 = *gw2, b2 = *gb2;
    const float g1 = *gg1, be1 = *gbe1, g2 = *gg2, be2 = *gbe2;
    const float LOG2E = 1.4426950408889634f;

    const float*  xrow  = xT + (size_t)r * LL;
    const float4* xrow4 = (const float4*)xrow;
    float* Mrow = MoT + (size_t)r * LL;
    const float4* mrow4 = (const float4*)Mrow;
    float4* orow4 = (float4*)Mrow;
    float4* lds4  = (float4*)s_ctx[wid];

    // ---- 1: top-40 via per-lane sorted top-4 cache + consume-mask rebuild
    {
        float cv0 = -3.4e38f, cv1 = -3.4e38f, cv2 = -3.4e38f, cv3 = -3.4e38f;
        int   ci0 = LL + 1,   ci1 = LL + 1,   ci2 = LL + 1,   ci3 = LL + 1;
#pragma unroll
        for (int m = 0; m < 8; ++m) {
            float4 w = mrow4[ln + m * 64];
            const int l0 = 4 * (ln + 64 * m);
            TOP4_INSERT(w.x, l0);
            TOP4_INSERT(w.y, l0 + 1);
            TOP4_INSERT(w.z, l0 + 2);
            TOP4_INSERT(w.w, l0 + 3);
        }
        unsigned int consumed = 0u;
        for (int t = 0; t < UU; ++t) {
            float rv = cv0; int ri = ci0;
#pragma unroll
            for (int off = 1; off < 64; off <<= 1) {
                float ov = __shfl_xor(rv, off, 64);
                int   oi = __shfl_xor(ri, off, 64);
                if (ov > rv || (ov == rv && oi < ri)) { rv = ov; ri = oi; }
            }
            if (ln == 0) s_top[wid][t] = ri;
            if (ci0 == ri) {                      // owner: consume + shift cache
                const int qq = ri & 3;
                const int mm = ((ri >> 2) - ln) >> 6;
                consumed |= (1u << (4 * mm + qq));
                cv0 = cv1; ci0 = ci1; cv1 = cv2; ci1 = ci2;
                cv2 = cv3; ci2 = ci3; cv3 = -3.4e38f; ci3 = LL + 1;
                if (ci0 == LL + 1) {              // cache empty: exact rebuild (rare)
                    cv0 = cv1 = cv2 = cv3 = -3.4e38f;
                    ci0 = ci1 = ci2 = ci3 = LL + 1;
#pragma unroll
                    for (int m = 0; m < 8; ++m) {
                        float4 w = mrow4[ln + m * 64];
                        const int l0 = 4 * (ln + 64 * m);
                        if (!(consumed & (1u << (4 * m + 0)))) TOP4_INSERT(w.x, l0);
                        if (!(consumed & (1u << (4 * m + 1)))) TOP4_INSERT(w.y, l0 + 1);
                        if (!(consumed & (1u << (4 * m + 2)))) TOP4_INSERT(w.z, l0 + 2);
                        if (!(consumed & (1u << (4 * m + 3)))) TOP4_INSERT(w.w, l0 + 3);
                    }
                }
            }
        }
    }

    // ---- 2: load x row; stats via monotone affine of x
    float4 xc[8];
    float vsum = 0.f, xmx = -3.4e38f, xmn = 3.4e38f;
#pragma unroll
    for (int m = 0; m < 8; ++m) {
        float4 xv = xrow4[ln + m * 64];
        xc[m] = xv;
        vsum += __fadd_rn(__fmul_rn(xv.x, Wv), bv) + __fadd_rn(__fmul_rn(xv.y, Wv), bv)
              + __fadd_rn(__fmul_rn(xv.z, Wv), bv) + __fadd_rn(__fmul_rn(xv.w, Wv), bv);
        xmx = fmaxf(xmx, fmaxf(fmaxf(xv.x, xv.y), fmaxf(xv.z, xv.w)));
        xmn = fminf(xmn, fminf(fminf(xv.x, xv.y), fminf(xv.z, xv.w)));
    }
    vsum = waveSum(vsum);
    xmx  = waveMax(xmx);
    xmn  = waveMin(xmn);
    const float vmean = vsum * (1.f / (float)LL);
    const float kmx = __fadd_rn(__fmul_rn((Wk >= 0.f) ? xmx : xmn, Wk), bk);
    const float kmn = __fadd_rn(__fmul_rn((Wk >= 0.f) ? xmn : xmx, Wk), bk);

    // ---- 3: ctx = vmean (wave-private LDS row)
#pragma unroll
    for (int m = 0; m < 8; ++m)
        lds4[ln + m * 64] = make_float4(vmean, vmean, vmean, vmean);

    // ---- 4: softmax, 10 groups of 4 u's. e = exp2(A*x + B),
    // A = qp*Wk*log2e, B = (qp*bk - smax)*log2e; Σe·v = Wv·Σe·x + bv·Σe
    for (int g = 0; g < UU / 4; ++g) {
        int p[4]; float A[4], Bc[4];
#pragma unroll
        for (int q = 0; q < 4; ++q) {
            p[q] = s_top[wid][g * 4 + q];
            const float xq = xrow[p[q]];
            const float qp = __fadd_rn(__fmul_rn(xq, Wq), bq);
            const float sm = (qp >= 0.f) ? __fmul_rn(qp, kmx) : __fmul_rn(qp, kmn);
            A[q]  = qp * Wk * LOG2E;
            Bc[q] = (qp * bk - sm) * LOG2E;
        }
        float se[4] = {0.f, 0.f, 0.f, 0.f};
        float sx[4] = {0.f, 0.f, 0.f, 0.f};
#pragma unroll
        for (int m = 0; m < 8; ++m) {
            float4 x4 = xc[m];
#pragma unroll
            for (int q = 0; q < 4; ++q) {
                float e;
                e = exp2f(fmaf(A[q], x4.x, Bc[q])); se[q] += e; sx[q] = fmaf(e, x4.x, sx[q]);
                e = exp2f(fmaf(A[q], x4.y, Bc[q])); se[q] += e; sx[q] = fmaf(e, x4.y, sx[q]);
                e = exp2f(fmaf(A[q], x4.z, Bc[q])); se[q] += e; sx[q] = fmaf(e, x4.z, sx[q]);
                e = exp2f(fmaf(A[q], x4.w, Bc[q])); se[q] += e; sx[q] = fmaf(e, x4.w, sx[q]);
            }
        }
#pragma unroll
        for (int q = 0; q < 4; ++q) {
            const float seA = waveSum(se[q]);
            const float sxA = waveSum(sx[q]);
            const float upd = (Wv * sxA + bv * seA) / seA;
            if (ln == 0) s_ctx[wid][p[q]] = upd;
        }
    }

    // ---- 5: epilogue (wave-local; same-wave LDS ordering is program order)
    float4 tt[8];
    float lsum = 0.f;
#pragma unroll
    for (int m = 0; m < 8; ++m) {
        float4 cx = lds4[ln + m * 64], xv = xc[m], tv;
        tv.x = xv.x + __fadd_rn(__fmul_rn(cx.x, Wo), bo);
        tv.y = xv.y + __fadd_rn(__fmul_rn(cx.y, Wo), bo);
        tv.z = xv.z + __fadd_rn(__fmul_rn(cx.z, Wo), bo);
        tv.w = xv.w + __fadd_rn(__fmul_rn(cx.w, Wo), bo);
        tt[m] = tv;
        lsum += tv.x + tv.y + tv.z + tv.w;
    }
    const float mean1 = waveSum(lsum) * (1.f / (float)LL);
    float lss = 0.f;
#pragma unroll
    for (int m = 0; m < 8; ++m) {
        float4 tv = tt[m];
        float d0 = tv.x - mean1, d1 = tv.y - mean1, d2 = tv.z - mean1, d3 = tv.w - mean1;
        lss += d0 * d0 + d1 * d1 + d2 * d2 + d3 * d3;
    }
    const float var1 = waveSum(lss) * (1.f / (float)LL);
    const float rs1 = rsqrtf(var1 + EPSF);

    float lsum2 = 0.f;
#pragma unroll
    for (int m = 0; m < 8; ++m) {
        float4 tv = tt[m], zz;
        {
            float x1 = (tv.x - mean1) * rs1 * g1 + be1;
            float a = x1 * w1 + b1;
            float y = 0.5f * a * (1.f + erff(a * 0.70710678118654752f));
            zz.x = x1 + (y * w2 + b2);
        }
        {
            float x1 = (tv.y - mean1) * rs1 * g1 + be1;
            float a = x1 * w1 + b1;
            float y = 0.5f * a * (1.f + erff(a * 0.70710678118654752f));
            zz.y = x1 + (y * w2 + b2);
        }
        {
            float x1 = (tv.z - mean1) * rs1 * g1 + be1;
            float a = x1 * w1 + b1;
            float y = 0.5f * a * (1.f + erff(a * 0.70710678118654752f));
            zz.z = x1 + (y * w2 + b2);
        }
        {
            float x1 = (tv.w - mean1) * rs1 * g1 + be1;
            float a = x1 * w1 + b1;
            float y = 0.5f * a * (1.f + erff(a * 0.70710678118654752f));
            zz.w = x1 + (y * w2 + b2);
        }
        tt[m] = zz;
        lsum2 += zz.x + zz.y + zz.z + zz.w;
    }
    const float mean2 = waveSum(lsum2) * (1.f / (float)LL);
    float lss2 = 0.f;
#pragma unroll
    for (int m = 0; m < 8; ++m) {
        float4 zz = tt[m];
        float d0 = zz.x - mean2, d1 = zz.y - mean2, d2 = zz.z - mean2, d3 = zz.w - mean2;
        lss2 += d0 * d0 + d1 * d1 + d2 * d2 + d3 * d3;
    }
    const float var2 = waveSum(lss2) * (1.f / (float)LL);
    const float rs2 = rsqrtf(var2 + EPSF);

#pragma unroll
    for (int m = 0; m < 8; ++m) {
        float4 zz = tt[m], oo;
        oo.x = (zz.x - mean2) * rs2 * g2 + be2;
        oo.y = (zz.y - mean2) * rs2 * g2 + be2;
        oo.z = (zz.z - mean2) * rs2 * g2 + be2;
        oo.w = (zz.w - mean2) * rs2 * g2 + be2;
        orow4[ln + m * 64] = oo;
    }
}

// ---------------- fallback (strided, self-contained; only if ws too small) ----------------
__global__ __launch_bounds__(NT) void informer_fallback(
    const float* __restrict__ xin,
    const float* __restrict__ gWq, const float* __restrict__ gbq,
    const float* __restrict__ gWk, const float* __restrict__ gbk,
    const float* __restrict__ gWv, const float* __restrict__ gbv,
    const float* __restrict__ gWo, const float* __restrict__ gbo,
    const float* __restrict__ gw1, const float* __restrict__ gb1,
    const float* __restrict__ gw2, const float* __restrict__ gb2,
    const float* __restrict__ gg1, const float* __restrict__ gbe1,
    const float* __restrict__ gg2, const float* __restrict__ gbe2,
    const int* __restrict__ idx,
    float* __restrict__ outp)
{
    const int tid  = threadIdx.x;
    const int lane = tid & 63;
    const int wid  = tid >> 6;
    const int blk  = blockIdx.x;
    const int b    = blk >> 7;
    const int c    = blk & (CC - 1);

    __shared__ float  s_xc[LL];
    __shared__ float  s_kc[LL];
    __shared__ float  s_v[LL];
    __shared__ float  s_red[NW];
    __shared__ double s_cv[NW * UU];
    __shared__ int    s_ci[NW * UU];
    __shared__ int    s_top[UU];
    __shared__ float  s_upd[UU];

    const float Wq = *gWq, bq = *gbq, Wk = *gWk, bk = *gbk;
    const float Wv = *gWv, bv = *gbv, Wo = *gWo, bo = *gbo;
    const float w1 = *gw1, b1 = *gb1, w2 = *gw2, b2 = *gb2;
    const float g1 = *gg1, be1 = *gbe1, g2 = *gg2, be2 = *gbe2;

    const float* xrow = xin + (size_t)b * LL * CC + c;
    float* orow = outp + (size_t)b * LL * CC + c;

    float vsum = 0.f, kmn = 3.4e38f, kmx = -3.4e38f;
    for (int l = tid; l < LL; l += NT) {
        float xv = xrow[(size_t)l * CC];
        s_xc[l] = xv;
        float kvv = __fadd_rn(__fmul_rn(xv, Wk), bk);
        float vvv = __fadd_rn(__fmul_rn(xv, Wv), bv);
        s_kc[l] = kvv;
        s_v[l] = vvv;
        vsum += vvv;
        kmn = fminf(kmn, kvv);
        kmx = fmaxf(kmx, kvv);
    }
    const float vmean  = blockSum(vsum, s_red) * (1.f / (float)LL);
    const float kmxAll = blockMax(kmx, s_red);
    const float kmnAll = blockMin(kmn, s_red);

    double mloc[8];
#pragma unroll
    for (int j = 0; j < 8; ++j) {
        const int l = tid + NT * j;
        const float qv = __fadd_rn(__fmul_rn(s_xc[l], Wq), bq);
        const double qd = (double)qv;
        const int* row = idx + l * UU;
        float kmaxs = -3.4e38f, kmins = 3.4e38f;
        double ssum = 0.0;
#pragma unroll 8
        for (int u = 0; u < UU; ++u) {
            float kvv = s_kc[row[u]];
            kmaxs = fmaxf(kmaxs, kvv);
            kmins = fminf(kmins, kvv);
            ssum += (double)kvv;
        }
        double qmax = (qd >= 0.0) ? qd * (double)kmaxs : qd * (double)kmins;
        mloc[j] = qmax - qd * ssum * (1.0 / (double)LL);
    }

    double wbv = mloc[0]; int wbi = tid;
#pragma unroll
    for (int j = 1; j < 8; ++j)
        if (mloc[j] > wbv) { wbv = mloc[j]; wbi = tid + NT * j; }

    for (int t = 0; t < UU; ++t) {
        double rv = wbv; int ri = wbi;
#pragma unroll
        for (int off = 1; off < 64; off <<= 1) {
            double ov = __shfl_xor(rv, off, 64);
            int    oi = __shfl_xor(ri, off, 64);
            if (ov > rv || (ov == rv && oi < ri)) { rv = ov; ri = oi; }
        }
        if (lane == 0) { s_cv[wid * UU + t] = rv; s_ci[wid * UU + t] = ri; }
        if (wbi == ri) {
#pragma unroll
            for (int j = 0; j < 8; ++j) if ((tid + NT * j) == ri) mloc[j] = -1e300;
            wbv = mloc[0]; wbi = tid;
#pragma unroll
            for (int j = 1; j < 8; ++j)
                if (mloc[j] > wbv) { wbv = mloc[j]; wbi = tid + NT * j; }
        }
    }
    __syncthreads();

    if (wid == 0) {
        double c0v = s_cv[lane], c1v = s_cv[lane + 64];
        int    c0i = s_ci[lane], c1i = s_ci[lane + 64];
        double c2v = (lane < 32) ? s_cv[lane + 128] : -1e300;
        int    c2i = (lane < 32) ? s_ci[lane + 128] : (LL + 1);
        for (int t = 0; t < UU; ++t) {
            double rv = c0v; int ri = c0i;
            if (c1v > rv || (c1v == rv && c1i < ri)) { rv = c1v; ri = c1i; }
            if (c2v > rv || (c2v == rv && c2i < ri)) { rv = c2v; ri = c2i; }
#pragma unroll
            for (int off = 1; off < 64; off <<= 1) {
                double ov = __shfl_xor(rv, off, 64);
                int    oi = __shfl_xor(ri, off, 64);
                if (ov > rv || (ov == rv && oi < ri)) { rv = ov; ri = oi; }
            }
            if (lane == 0) s_top[t] = ri;
            if (c0i == ri) c0v = -1e300;
            else if (c1i == ri) c1v = -1e300;
            else if (c2i == ri) c2v = -1e300;
        }
    }
    __syncthreads();

    for (int r = 0; r < UU / NW; ++r) {
        const int u = r * NW + wid;
        const int p = s_top[u];
        const float qp = __fadd_rn(__fmul_rn(s_xc[p], Wq), bq);
        const float smax = (qp >= 0.f) ? qp * kmxAll : qp * kmnAll;
        float se = 0.f, sev = 0.f;
        for (int l = lane; l < LL; l += 64) {
            float e = __expf(qp * s_kc[l] - smax);
            se += e;
            sev = fmaf(e, s_v[l], sev);
        }
        se = waveSum(se); sev = waveSum(sev);
        if (lane == 0) s_upd[u] = sev / se;
    }
    __syncthreads();

    for (int l = tid; l < LL; l += NT) s_kc[l] = vmean;
    __syncthreads();
    if (tid < UU) s_kc[s_top[tid]] = s_upd[tid];
    __syncthreads();

    float lsum = 0.f;
    for (int l = tid; l < LL; l += NT) {
        float tv = s_xc[l] + __fadd_rn(__fmul_rn(s_kc[l], Wo), bo);
        s_kc[l] = tv;
        lsum += tv;
    }
    const float mean1 = blockSum(lsum, s_red) * (1.f / (float)LL);
    float lss = 0.f;
    for (int l = tid; l < LL; l += NT) { float d = s_kc[l] - mean1; lss += d * d; }
    const float var1 = blockSum(lss, s_red) * (1.f / (float)LL);
    const float rs1 = rsqrtf(var1 + EPSF);

    float lsum2 = 0.f;
    for (int l = tid; l < LL; l += NT) {
        float x1 = (s_kc[l] - mean1) * rs1 * g1 + be1;
        float a  = x1 * w1 + b1;
        float y  = 0.5f * a * (1.f + erff(a * 0.70710678118654752f));
        y = y * w2 + b2;
        float z = x1 + y;
        s_kc[l] = z;
        lsum2 += z;
    }
    const float mean2 = blockSum(lsum2, s_red) * (1.f / (float)LL);
    float lss2 = 0.f;
    for (int l = tid; l < LL; l += NT) { float d = s_kc[l] - mean2; lss2 += d * d; }
    const float var2 = blockSum(lss2, s_red) * (1.f / (float)LL);
    const float rs2 = rsqrtf(var2 + EPSF);

    for (int l = tid; l < LL; l += NT)
        orow[(size_t)l * CC] = (s_kc[l] - mean2) * rs2 * g2 + be2;
}

extern "C" void kernel_launch(void* const* d_in, const int* in_sizes, int n_in,
                              void* d_out, int out_size, void* d_ws, size_t ws_size,
                              hipStream_t stream) {
    const float* x   = (const float*)d_in[0];
    const float* Wq  = (const float*)d_in[1];
    const float* bq  = (const float*)d_in[2];
    const float* Wk  = (const float*)d_in[3];
    const float* bk  = (const float*)d_in[4];
    const float* Wv  = (const float*)d_in[5];
    const float* bv  = (const float*)d_in[6];
    const float* Wo  = (const float*)d_in[7];
    const float* bo  = (const float*)d_in[8];
    const float* w1  = (const float*)d_in[9];
    const float* b1  = (const float*)d_in[10];
    const float* w2  = (const float*)d_in[11];
    const float* b2  = (const float*)d_in[12];
    const float* g1  = (const float*)d_in[13];
    const float* be1 = (const float*)d_in[14];
    const float* g2  = (const float*)d_in[15];
    const float* be2 = (const float*)d_in[16];
    const int*   idx = (const int*)d_in[17];
    float* out = (float*)d_out;

    const size_t SZ = (size_t)BB * LL * CC * sizeof(float);  // 16 MB

    if (ws_size >= 2 * SZ) {
        float* xT = (float*)d_ws;
        float* MT = (float*)((char*)d_ws + SZ);   // becomes outT in-place
        // 1) M[B,L,C] into d_out (coalesced writes; overwritten at the end)
        agg_kernel<<<dim3((LL / 8) * BB), dim3(256), 0, stream>>>(x, idx, Wq, bq, Wk, bk, out);
        // 2) transpose x->xT and M->MT in one launch
        transpose_dual<<<dim3(CC / 32, LL / 32, 2 * BB), dim3(32, 8), 0, stream>>>(x, xT, out, MT);
        // 3) wave-per-row: cheap top-40 + exp2 softmax + epilogue; writes over MT
        rowBC<<<dim3(BB * CC / 4), dim3(NT), 0, stream>>>(
            xT, MT, Wq, bq, Wk, bk, Wv, bv, Wo, bo, w1, b1, w2, b2,
            g1, be1, g2, be2);
        // 4) transpose back into d_out
        transpose_out<<<dim3(LL / 32, CC / 32, BB), dim3(32, 8), 0, stream>>>(MT, out);
    } else {
        informer_fallback<<<dim3(BB * CC), dim3(NT), 0, stream>>>(
            x, Wq, bq, Wk, bk, Wv, bv, Wo, bo, w1, b1, w2, b2,
            g1, be1, g2, be2, idx, out);
    }
}